// Round 4
// baseline (2041.456 us; speedup 1.0000x reference)
//
#include <hip/hip_runtime.h>
#include <hip/hip_bf16.h>
#include <cstdint>

#define DEV __device__ __forceinline__

typedef __hip_bfloat16 bf16;
typedef unsigned short u16;
typedef unsigned int u32;
typedef __attribute__((ext_vector_type(8))) short s8v;   // 8 bf16 (4 VGPRs) MFMA A/B frag
typedef __attribute__((ext_vector_type(4))) float f4;    // MFMA C/D frag

static constexpr int Bn = 128;
static constexpr int Tn = 256;
static constexpr int Dn = 384;
static constexpr int Hn = 6;
static constexpr int HDn = 64;
static constexpr int FFn = 1536;
static constexpr int Vn = 95;
static constexpr int Mn = Bn * Tn;   // 32768
static constexpr int QKS = 768;      // combined q|k row stride

DEV u16 f2b(float f) {
  bf16 h = __float2bfloat16(f);
  return *reinterpret_cast<u16*>(&h);
}
DEV u32 pk2(float a, float b) { return (u32)f2b(a) | ((u32)f2b(b) << 16); }

// async 16B global->LDS. LDS destination is wave-uniform base + lane*16.
DEV void gl_lds16(const void* g, void* l) {
  auto gp = (const __attribute__((address_space(1))) u32*)(uintptr_t)g;
  auto lp = (__attribute__((address_space(3))) u32*)(u32)(uintptr_t)l;
  __builtin_amdgcn_global_load_lds(gp, lp, 16, 0, 0);
}

// ---------------------------------------------------------------------------
// GEMM: C[M,N] = A[M,K] (bf16) * Bt[N,K]^T (bf16) [+bias] [+resid] [relu]
// MODE 0: bf16 out [M,N] (swapped acc: 4 consecutive n per lane -> 8B stores)
// MODE 1: f32 out = resid + C + bias [M,N] (swapped: float4 load/store)
// MODE 2: bf16 vT out [(b*H+h)][d][t] (UNswapped: 4 consecutive t per lane)
// MODE 3: f32 head out [M,95] (swapped, col-guarded scalar stores)
// 128x128 tile, BK=64, 4 waves (2x2), wave 64x64 = 4x4 MFMA tiles.
// LDS XOR-swizzled in 8-elem chunks. Block order: XCD-major (blk&7 = xcd,
// n-tiles consecutive per m-tile within an XCD) for A-tile L2 reuse.
// ---------------------------------------------------------------------------
template <int MODE, bool RELU>
__global__ __launch_bounds__(256) void gemm_bt(
    const u16* __restrict__ A, const u16* __restrict__ Bt,
    const float* __restrict__ bias, const float* __restrict__ resid,
    void* __restrict__ outp, int N, int K, int nTiles)
{
  __shared__ __align__(16) u16 As[128 * 64];
  __shared__ __align__(16) u16 Bs[128 * 64];
  const int tid = threadIdx.x;
  const int lane = tid & 63, wave = tid >> 6;
  const int quad = lane >> 4, l16 = lane & 15;
  const int wy = wave >> 1, wx = wave & 1;
  const int blk = blockIdx.x;
  const int xcd = blk & 7, tt = blk >> 3;
  const int nT = tt % nTiles, mT = xcd + 8 * (tt / nTiles);
  const int mBase = mT * 128, nBase = nT * 128;

  f4 acc[4][4] = {};

  int rS[4], cS[4];
#pragma unroll
  for (int i = 0; i < 4; i++) {
    int s = i * 256 + tid;
    rS[i] = s >> 3;
    cS[i] = ((s & 7) ^ (rS[i] & 7)) * 8;
  }

  for (int kt = 0; kt < K; kt += 64) {
#pragma unroll
    for (int i = 0; i < 4; i++) {
      gl_lds16(A + (mBase + rS[i]) * K + kt + cS[i], &As[(i * 256 + wave * 64) * 8]);
      gl_lds16(Bt + (nBase + rS[i]) * K + kt + cS[i], &Bs[(i * 256 + wave * 64) * 8]);
    }
    __syncthreads();
#pragma unroll
    for (int ks = 0; ks < 2; ks++) {
      s8v af[4], bfr[4];
#pragma unroll
      for (int i = 0; i < 4; i++) {
        int row = wy * 64 + i * 16 + l16;
        int ch = (ks * 4 + quad) ^ (row & 7);
        af[i] = *(const s8v*)&As[row * 64 + ch * 8];
      }
#pragma unroll
      for (int j = 0; j < 4; j++) {
        int row = wx * 64 + j * 16 + l16;
        int ch = (ks * 4 + quad) ^ (row & 7);
        bfr[j] = *(const s8v*)&Bs[row * 64 + ch * 8];
      }
#pragma unroll
      for (int i = 0; i < 4; i++)
#pragma unroll
        for (int j = 0; j < 4; j++) {
          if (MODE == 2)
            acc[i][j] = __builtin_amdgcn_mfma_f32_16x16x32_bf16(af[i], bfr[j], acc[i][j], 0, 0, 0);
          else  // swapped: D rows <- n (first operand), cols <- m
            acc[i][j] = __builtin_amdgcn_mfma_f32_16x16x32_bf16(bfr[j], af[i], acc[i][j], 0, 0, 0);
        }
    }
    __syncthreads();
  }

  if (MODE == 0) {
    u16* out = (u16*)outp;
#pragma unroll
    for (int i = 0; i < 4; i++) {
      int m = mBase + wy * 64 + i * 16 + l16;
#pragma unroll
      for (int j = 0; j < 4; j++) {
        int n0 = nBase + wx * 64 + j * 16 + quad * 4;
        float4 bv = bias ? *(const float4*)&bias[n0] : make_float4(0.f, 0.f, 0.f, 0.f);
        float v0 = acc[i][j][0] + bv.x, v1 = acc[i][j][1] + bv.y;
        float v2 = acc[i][j][2] + bv.z, v3 = acc[i][j][3] + bv.w;
        if (RELU) {
          v0 = fmaxf(v0, 0.f); v1 = fmaxf(v1, 0.f);
          v2 = fmaxf(v2, 0.f); v3 = fmaxf(v3, 0.f);
        }
        uint2 w;
        w.x = pk2(v0, v1);
        w.y = pk2(v2, v3);
        *(uint2*)&out[m * N + n0] = w;
      }
    }
  } else if (MODE == 1) {
    float* out = (float*)outp;
#pragma unroll
    for (int i = 0; i < 4; i++) {
      int m = mBase + wy * 64 + i * 16 + l16;
#pragma unroll
      for (int j = 0; j < 4; j++) {
        int n0 = nBase + wx * 64 + j * 16 + quad * 4;
        float4 rv = *(const float4*)&resid[m * N + n0];
        float4 bv = *(const float4*)&bias[n0];
        float4 o;
        o.x = rv.x + acc[i][j][0] + bv.x;
        o.y = rv.y + acc[i][j][1] + bv.y;
        o.z = rv.z + acc[i][j][2] + bv.z;
        o.w = rv.w + acc[i][j][3] + bv.w;
        *(float4*)&out[m * N + n0] = o;
      }
    }
  } else if (MODE == 3) {
    float* out = (float*)outp;
#pragma unroll
    for (int i = 0; i < 4; i++) {
      int m = mBase + wy * 64 + i * 16 + l16;
#pragma unroll
      for (int j = 0; j < 4; j++) {
        int n0 = nBase + wx * 64 + j * 16 + quad * 4;
#pragma unroll
        for (int r = 0; r < 4; r++) {
          int n = n0 + r;
          if (n < Vn) out[m * Vn + n] = acc[i][j][r] + bias[n];
        }
      }
    }
  } else {  // MODE 2: vT out, acc unswapped (rows=m: 4 consecutive t per lane)
    u16* out = (u16*)outp;
#pragma unroll
    for (int j = 0; j < 4; j++) {
      int n = nBase + wx * 64 + j * 16 + l16;
      int hh = n >> 6, d = n & 63;
#pragma unroll
      for (int i = 0; i < 4; i++) {
        int m0 = mBase + wy * 64 + i * 16 + quad * 4;
        int b = m0 >> 8, t0 = m0 & 255;
        uint2 w;
        w.x = pk2(acc[i][j][0], acc[i][j][1]);
        w.y = pk2(acc[i][j][2], acc[i][j][3]);
        *(uint2*)&out[((b * Hn + hh) * HDn + d) * Tn + t0] = w;
      }
    }
  }
}

// ---------------------------------------------------------------------------
// Flash-chunked attention. Grid = B*H*4 blocks; block (bh, c4); wave w handles
// ONE q-tile qt in {c4, 7-c4, 8+c4, 15-c4} -> identical work per block.
// q/k read from combined qk buffer (row stride QKS=768).
// ---------------------------------------------------------------------------
__global__ __launch_bounds__(256) void attn_kernel(
    const u16* __restrict__ qk, const u16* __restrict__ vT,
    u16* __restrict__ ao)
{
  __shared__ __align__(16) u16 Ps[4][16 * 40];
  const int tid = threadIdx.x, lane = tid & 63, wave = tid >> 6;
  const int quad = lane >> 4, l16 = lane & 15;
  const int bh = blockIdx.x >> 2, c4 = blockIdx.x & 3;
  const int b = bh / Hn, h = bh % Hn;
  const u16* qg = qk + (size_t)(b * Tn) * QKS + h * HDn;
  const u16* kg = qg + 384;
  const u16* vg = vT + bh * (HDn * Tn);
  u16* aog = ao + (b * Tn) * Dn + h * HDn;
  const float c1 = 0.125f * 1.44269504f;  // scale * log2(e)

  const int qt = (wave & 2) ? ((wave & 1) ? 15 - c4 : 8 + c4)
                            : ((wave & 1) ? 7 - c4 : c4);
  const int qglob = qt * 16 + l16;

  const s8v qf0 = *(const s8v*)&qg[qglob * QKS + quad * 8];
  const s8v qf1 = *(const s8v*)&qg[qglob * QKS + 32 + quad * 8];

  float m = -3.0e38f, l = 0.f;
  f4 O[4] = {};
  u16* prow = &Ps[wave][l16 * 40];

  const int nch = qt / 2 + 1;
  for (int c2 = 0; c2 < nch; c2++) {
    const int kk0 = c2 * 32;
    f4 S0 = {0.f, 0.f, 0.f, 0.f}, S1 = S0;
    {
      s8v kf = *(const s8v*)&kg[(kk0 + l16) * QKS + quad * 8];
      S0 = __builtin_amdgcn_mfma_f32_16x16x32_bf16(kf, qf0, S0, 0, 0, 0);
      kf = *(const s8v*)&kg[(kk0 + l16) * QKS + 32 + quad * 8];
      S0 = __builtin_amdgcn_mfma_f32_16x16x32_bf16(kf, qf1, S0, 0, 0, 0);
    }
    if (kk0 + 16 <= qt * 16) {  // second 16-row K tile inside causal bound
      s8v kf = *(const s8v*)&kg[(kk0 + 16 + l16) * QKS + quad * 8];
      S1 = __builtin_amdgcn_mfma_f32_16x16x32_bf16(kf, qf0, S1, 0, 0, 0);
      kf = *(const s8v*)&kg[(kk0 + 16 + l16) * QKS + 32 + quad * 8];
      S1 = __builtin_amdgcn_mfma_f32_16x16x32_bf16(kf, qf1, S1, 0, 0, 0);
    }
    const int kkq = kk0 + quad * 4;
    float cmax = -3.0e38f;
#pragma unroll
    for (int r = 0; r < 4; r++) {
      if (kkq + r <= qglob) cmax = fmaxf(cmax, S0[r]);
      if (kkq + 16 + r <= qglob) cmax = fmaxf(cmax, S1[r]);
    }
    cmax = fmaxf(cmax, __shfl_xor(cmax, 16));
    cmax = fmaxf(cmax, __shfl_xor(cmax, 32));
    const float mnew = fmaxf(m, cmax);
    const float alpha = exp2f((m - mnew) * c1);
    float csum = 0.f;
#pragma unroll
    for (int r = 0; r < 4; r++) {
      float e0 = (kkq + r <= qglob) ? exp2f((S0[r] - mnew) * c1) : 0.f;
      float e1 = (kkq + 16 + r <= qglob) ? exp2f((S1[r] - mnew) * c1) : 0.f;
      S0[r] = e0;
      S1[r] = e1;
      csum += e0 + e1;
    }
    csum += __shfl_xor(csum, 16);
    csum += __shfl_xor(csum, 32);
    l = l * alpha + csum;
    m = mnew;

    uint2 w0, w1;
    w0.x = pk2(S0[0], S0[1]); w0.y = pk2(S0[2], S0[3]);
    w1.x = pk2(S1[0], S1[1]); w1.y = pk2(S1[2], S1[3]);
    *(uint2*)&prow[quad * 4] = w0;
    *(uint2*)&prow[16 + quad * 4] = w1;
#pragma unroll
    for (int dm = 0; dm < 4; dm++) O[dm] = O[dm] * alpha;
    const s8v pf = *(const s8v*)&prow[quad * 8];
#pragma unroll
    for (int dm = 0; dm < 4; dm++) {
      s8v vf = *(const s8v*)&vg[(dm * 16 + l16) * Tn + kk0 + quad * 8];
      O[dm] = __builtin_amdgcn_mfma_f32_16x16x32_bf16(vf, pf, O[dm], 0, 0, 0);
    }
  }

  const float inv = 1.0f / l;
#pragma unroll
  for (int dm = 0; dm < 4; dm++) {
    uint2 w;
    w.x = pk2(O[dm][0] * inv, O[dm][1] * inv);
    w.y = pk2(O[dm][2] * inv, O[dm][3] * inv);
    *(uint2*)&aog[qglob * Dn + dm * 16 + quad * 4] = w;
  }
}

// ---------------------------------------------------------------------------
// LayerNorm: one wave per token (D=384 -> 6 floats/lane), bf16 out.
// ---------------------------------------------------------------------------
__global__ __launch_bounds__(256) void ln_kernel(
    const float* __restrict__ x, const float* __restrict__ sc,
    const float* __restrict__ bi, u16* __restrict__ out)
{
  int tok = blockIdx.x * 4 + (threadIdx.x >> 6);
  int lane = threadIdx.x & 63;
  const float* xr = x + (size_t)tok * Dn;
  float v[6];
  float s = 0.f, sq = 0.f;
#pragma unroll
  for (int i = 0; i < 6; i++) {
    v[i] = xr[lane + 64 * i];
    s += v[i];
    sq += v[i] * v[i];
  }
#pragma unroll
  for (int o = 1; o < 64; o <<= 1) {
    s += __shfl_xor(s, o);
    sq += __shfl_xor(sq, o);
  }
  float mean = s * (1.f / 384.f);
  float var = sq * (1.f / 384.f) - mean * mean;
  float inv = rsqrtf(var + 1e-5f);
  u16* orow = out + (size_t)tok * Dn;
#pragma unroll
  for (int i = 0; i < 6; i++) {
    int c = lane + 64 * i;
    orow[c] = f2b((v[i] - mean) * inv * sc[c] + bi[c]);
  }
}

// x[m][:] = tok_emb[idx[m]][:] + pos_emb[m%T][:]  (float4 per thread)
__global__ __launch_bounds__(256) void embed_kernel(
    const int* __restrict__ idx, const float* __restrict__ tok,
    const float* __restrict__ pos, float* __restrict__ x)
{
  int i = blockIdx.x * 256 + threadIdx.x;  // [0, M*96)
  int m = i / 96, c = (i - m * 96) * 4;
  int t = m & (Tn - 1);
  const float4 tv = *(const float4*)&tok[idx[m] * Dn + c];
  const float4 pv = *(const float4*)&pos[t * Dn + c];
  float4 r;
  r.x = tv.x + pv.x; r.y = tv.y + pv.y; r.z = tv.z + pv.z; r.w = tv.w + pv.w;
  *(float4*)&x[m * Dn + c] = r;
}

// dst[l*lstride + c*R + r] (bf16, zero-filled c>=C) = src[l][r][c] (f32)
__global__ __launch_bounds__(256) void tcvt_kernel(
    const float* __restrict__ src, u16* __restrict__ dst,
    int R, int C, int Cpad, int lstride, int total)
{
  int t = blockIdx.x * 256 + threadIdx.x;
  if (t >= total) return;
  int r = t % R;
  int c = (t / R) % Cpad;
  int l = t / (R * Cpad);
  float v = (c < C) ? src[l * R * C + r * C + c] : 0.f;
  dst[l * lstride + c * R + r] = f2b(v);
}

extern "C" void kernel_launch(void* const* d_in, const int* in_sizes, int n_in,
                              void* d_out, int out_size, void* d_ws, size_t ws_size,
                              hipStream_t stream)
{
  (void)in_sizes; (void)n_in; (void)out_size;
  const int*   idx     = (const int*)d_in[0];
  const float* tok_emb = (const float*)d_in[1];
  const float* pos_emb = (const float*)d_in[2];
  const float* ln1_s   = (const float*)d_in[3];
  const float* ln1_b   = (const float*)d_in[4];
  const float* wq      = (const float*)d_in[5];
  const float* wk      = (const float*)d_in[6];
  const float* wv      = (const float*)d_in[7];
  const float* wo      = (const float*)d_in[8];
  const float* bo      = (const float*)d_in[9];
  const float* ln2_s   = (const float*)d_in[10];
  const float* ln2_b   = (const float*)d_in[11];
  const float* w1      = (const float*)d_in[12];
  const float* b1      = (const float*)d_in[13];
  const float* w2      = (const float*)d_in[14];
  const float* b2      = (const float*)d_in[15];
  const float* lnf_s   = (const float*)d_in[16];
  const float* lnf_b   = (const float*)d_in[17];
  const float* head_w  = (const float*)d_in[18];
  const float* head_b  = (const float*)d_in[19];
  float* out = (float*)d_out;

  // workspace layout (bytes)
  char* ws = (char*)d_ws;
  float* x  = (float*)(ws + 0);             // 50,331,648  fp32 residual stream
  u16*   h  = (u16*)(ws + 50331648);        // 25,165,824  LN output (bf16)
  u16*   qk = (u16*)(ws + 75497472);        // 50,331,648  combined q|k [M,768]
  u16*   vb = (u16*)(ws + 125829120);       // 25,165,824  V^T [(b,h)][d][t]
  u16*   ab = (u16*)(ws + 150994944);       // 25,165,824  attn out
  u16*   f1 = qk;                           // alias (qk+vb+ab = 96 MB) FFN1 out
  u16* qkT = (u16*)(ws + 176160768);        // 6 * 768*384 (q rows then k rows)
  u16* wvT = qkT + 6 * 294912;              // 6 * 147456
  u16* woT = wvT + 6 * 147456;              // 6 * 147456
  u16* w1T = woT + 6 * 147456;              // 6 * 589824  [FF,K=D]
  u16* w2T = w1T + 6 * 589824;              // 6 * 589824  [D,K=FF]
  u16* hdT = w2T + 6 * 589824;              // 128*384, N padded 95->128
  if (ws_size < (size_t)197492736) return;

  int tot = 6 * 384 * 384;
  tcvt_kernel<<<(tot + 255) / 256, 256, 0, stream>>>(wq, qkT, 384, 384, 384, 294912, tot);
  tcvt_kernel<<<(tot + 255) / 256, 256, 0, stream>>>(wk, qkT + 384 * 384, 384, 384, 384, 294912, tot);
  tcvt_kernel<<<(tot + 255) / 256, 256, 0, stream>>>(wv, wvT, 384, 384, 384, 147456, tot);
  tcvt_kernel<<<(tot + 255) / 256, 256, 0, stream>>>(wo, woT, 384, 384, 384, 147456, tot);
  tot = 6 * 1536 * 384;
  tcvt_kernel<<<(tot + 255) / 256, 256, 0, stream>>>(w1, w1T, 384, 1536, 1536, 589824, tot);
  tcvt_kernel<<<(tot + 255) / 256, 256, 0, stream>>>(w2, w2T, 1536, 384, 384, 589824, tot);
  tot = 128 * 384;
  tcvt_kernel<<<(tot + 255) / 256, 256, 0, stream>>>(head_w, hdT, 384, 95, 128, 49152, tot);

  embed_kernel<<<(Mn * 96) / 256, 256, 0, stream>>>(idx, tok_emb, pos_emb, x);

  for (int l = 0; l < 6; l++) {
    ln_kernel<<<Mn / 4, 256, 0, stream>>>(x, ln1_s + l * Dn, ln1_b + l * Dn, h);
    gemm_bt<0, false><<<1536, 256, 0, stream>>>(h, qkT + l * 294912, nullptr, nullptr, qk, 768, Dn, 6);
    gemm_bt<2, false><<<768, 256, 0, stream>>>(h, wvT + l * 147456, nullptr, nullptr, vb, Dn, Dn, 3);
    attn_kernel<<<Bn * Hn * 4, 256, 0, stream>>>(qk, vb, ab);
    gemm_bt<1, false><<<768, 256, 0, stream>>>(ab, woT + l * 147456, bo + l * Dn, x, x, Dn, Dn, 3);
    ln_kernel<<<Mn / 4, 256, 0, stream>>>(x, ln2_s + l * Dn, ln2_b + l * Dn, h);
    gemm_bt<0, true><<<3072, 256, 0, stream>>>(h, w1T + l * 589824, b1 + l * FFn, nullptr, f1, FFn, Dn, 12);
    gemm_bt<1, false><<<768, 256, 0, stream>>>(f1, w2T + l * 589824, b2 + l * Dn, x, x, Dn, FFn, 3);
  }
  ln_kernel<<<Mn / 4, 256, 0, stream>>>(x, lnf_s, lnf_b, h);
  gemm_bt<3, false><<<256, 256, 0, stream>>>(h, hdT, head_b, nullptr, out, 128, Dn, 1);
}

// Round 5
// 1693.303 us; speedup vs baseline: 1.2056x; 1.2056x over previous
//
#include <hip/hip_runtime.h>
#include <hip/hip_bf16.h>
#include <cstdint>

#define DEV __device__ __forceinline__

typedef __hip_bfloat16 bf16;
typedef unsigned short u16;
typedef unsigned int u32;
typedef __attribute__((ext_vector_type(8))) short s8v;   // 8 bf16 (4 VGPRs) MFMA A/B frag
typedef __attribute__((ext_vector_type(4))) float f4;    // MFMA C/D frag

static constexpr int Bn = 128;
static constexpr int Tn = 256;
static constexpr int Dn = 384;
static constexpr int Hn = 6;
static constexpr int HDn = 64;
static constexpr int FFn = 1536;
static constexpr int Vn = 95;
static constexpr int Mn = Bn * Tn;   // 32768

DEV u16 f2b(float f) {
  bf16 h = __float2bfloat16(f);
  return *reinterpret_cast<u16*>(&h);
}
DEV u32 pk2(float a, float b) { return (u32)f2b(a) | ((u32)f2b(b) << 16); }

// async 16B global->LDS. LDS destination is wave-uniform base + lane*16.
DEV void gl_lds16(const void* g, void* l) {
  auto gp = (const __attribute__((address_space(1))) u32*)(uintptr_t)g;
  auto lp = (__attribute__((address_space(3))) u32*)(u32)(uintptr_t)l;
  __builtin_amdgcn_global_load_lds(gp, lp, 16, 0, 0);
}

// ---------------------------------------------------------------------------
// GEMM: C[M,N] = A[M,K] (bf16) * Bt[N,K]^T (bf16) [+bias] [+resid] [relu]
// MODE 0: bf16 out [M,N]     MODE 1: f32 out = resid + C + bias [M,N]
// MODE 3: f32 head out [M,95], col-guarded
// MODE 4: fused QKV: n<384 -> q bf16[M,384]; n<768 -> k; n>=768 -> vT layout
// 128x128 tile, BK=64, 4 waves (2x2), wave 64x64 = 4x4 MFMA tiles.
// DOUBLE-BUFFERED K-loop with raw-asm barriers + s_waitcnt vmcnt(8): the
// next tile's global_load_lds stay in flight across the barrier and the
// MFMAs (AITER-style; __syncthreads would drain vmcnt(0) = the m97 stall).
// Ordering per iter: s_barrier (all compute(i-1) done -> safe to overwrite
// buf (i+1)&1) ; issue stage(i+1) ; vmcnt(8) (own stage(i) done) ; s_barrier
// (everyone's stage(i) done) ; MFMA on buf i&1.
// LDS XOR-swizzled in 8-elem chunks. Block order: XCD-major for A L2 reuse.
// ---------------------------------------------------------------------------
template <int MODE, bool RELU>
__global__ __launch_bounds__(256) void gemm_bt(
    const u16* __restrict__ A, const u16* __restrict__ Bt,
    const float* __restrict__ bias, const float* __restrict__ resid,
    void* __restrict__ outp, int N, int K, int nTiles)
{
  __shared__ __align__(16) u16 As[2][128 * 64];
  __shared__ __align__(16) u16 Bs[2][128 * 64];
  const int tid = threadIdx.x;
  const int lane = tid & 63, wave = tid >> 6;
  const int quad = lane >> 4, l16 = lane & 15;
  const int wy = wave >> 1, wx = wave & 1;
  const int blk = blockIdx.x;
  const int xcd = blk & 7, tt = blk >> 3;
  const int nT = tt % nTiles, mT = xcd + 8 * (tt / nTiles);
  const int mBase = mT * 128, nBase = nT * 128;

  f4 acc[4][4] = {};

  int rS[4], cS[4];
#pragma unroll
  for (int i = 0; i < 4; i++) {
    int s = i * 256 + tid;
    rS[i] = s >> 3;
    cS[i] = ((s & 7) ^ (rS[i] & 7)) * 8;
  }

  const u16* Ab = A + mBase * K;
  const u16* Bb = Bt + nBase * K;

#define STAGE(buf, kt)                                                        \
  do {                                                                        \
    _Pragma("unroll")                                                         \
    for (int i = 0; i < 4; i++)                                               \
      gl_lds16(Ab + rS[i] * K + (kt) + cS[i], &As[buf][(i * 256 + wave * 64) * 8]); \
    _Pragma("unroll")                                                         \
    for (int i = 0; i < 4; i++)                                               \
      gl_lds16(Bb + rS[i] * K + (kt) + cS[i], &Bs[buf][(i * 256 + wave * 64) * 8]); \
  } while (0)

  STAGE(0, 0);
  const int nk = K >> 6;
  for (int ik = 0; ik < nk; ik++) {
    const int cur = ik & 1;
    asm volatile("s_barrier" ::: "memory");
    if (ik + 1 < nk) {
      STAGE(cur ^ 1, (ik + 1) * 64);
      asm volatile("s_waitcnt vmcnt(8)" ::: "memory");
    } else {
      asm volatile("s_waitcnt vmcnt(0)" ::: "memory");
    }
    asm volatile("s_barrier" ::: "memory");
#pragma unroll
    for (int ks = 0; ks < 2; ks++) {
      s8v af[4], bfr[4];
#pragma unroll
      for (int i = 0; i < 4; i++) {
        int row = wy * 64 + i * 16 + l16;
        int ch = (ks * 4 + quad) ^ (row & 7);
        af[i] = *(const s8v*)&As[cur][row * 64 + ch * 8];
      }
#pragma unroll
      for (int j = 0; j < 4; j++) {
        int row = wx * 64 + j * 16 + l16;
        int ch = (ks * 4 + quad) ^ (row & 7);
        bfr[j] = *(const s8v*)&Bs[cur][row * 64 + ch * 8];
      }
#pragma unroll
      for (int i = 0; i < 4; i++)
#pragma unroll
        for (int j = 0; j < 4; j++)
          acc[i][j] = __builtin_amdgcn_mfma_f32_16x16x32_bf16(af[i], bfr[j], acc[i][j], 0, 0, 0);
    }
  }
#undef STAGE

  // epilogue (R3 layouts): C(i,j,r): m = mBase+wy*64+i*16+quad*4+r, n = nBase+wx*64+j*16+l16
  if (MODE == 0) {
    u16* out = (u16*)outp;
#pragma unroll
    for (int j = 0; j < 4; j++) {
      int n = nBase + wx * 64 + j * 16 + l16;
      float bv = bias ? bias[n] : 0.f;
#pragma unroll
      for (int i = 0; i < 4; i++) {
        int m0 = mBase + wy * 64 + i * 16 + quad * 4;
#pragma unroll
        for (int r = 0; r < 4; r++) {
          float v = acc[i][j][r] + bv;
          if (RELU) v = fmaxf(v, 0.f);
          out[(m0 + r) * N + n] = f2b(v);
        }
      }
    }
  } else if (MODE == 1) {
    float* out = (float*)outp;
#pragma unroll
    for (int j = 0; j < 4; j++) {
      int n = nBase + wx * 64 + j * 16 + l16;
      float bv = bias[n];
#pragma unroll
      for (int i = 0; i < 4; i++) {
        int m0 = mBase + wy * 64 + i * 16 + quad * 4;
#pragma unroll
        for (int r = 0; r < 4; r++) {
          int m = m0 + r;
          out[m * N + n] = resid[m * N + n] + acc[i][j][r] + bv;
        }
      }
    }
  } else if (MODE == 3) {
    float* out = (float*)outp;
#pragma unroll
    for (int j = 0; j < 4; j++) {
      int n = nBase + wx * 64 + j * 16 + l16;
      if (n < Vn) {
        float bv = bias[n];
#pragma unroll
        for (int i = 0; i < 4; i++) {
          int m0 = mBase + wy * 64 + i * 16 + quad * 4;
#pragma unroll
          for (int r = 0; r < 4; r++)
            out[(m0 + r) * Vn + n] = acc[i][j][r] + bv;
        }
      }
    }
  } else if (MODE == 4) {
    u16* qb = (u16*)outp;
    u16* kb = qb + (size_t)Mn * 384;
    u16* vb = kb + (size_t)Mn * 384;
#pragma unroll
    for (int j = 0; j < 4; j++) {
      int n = nBase + wx * 64 + j * 16 + l16;
      if (n < 768) {
        u16* dst = (n < 384) ? qb : kb;
        int col = (n < 384) ? n : (n - 384);   // 384 is NOT pow2 — no mask!
#pragma unroll
        for (int i = 0; i < 4; i++) {
          int m0 = mBase + wy * 64 + i * 16 + quad * 4;
#pragma unroll
          for (int r = 0; r < 4; r++)
            dst[(m0 + r) * 384 + col] = f2b(acc[i][j][r]);
        }
      } else {
        int n7 = n - 768;
        int hh = n7 >> 6, d = n7 & 63;
#pragma unroll
        for (int i = 0; i < 4; i++) {
          int m0 = mBase + wy * 64 + i * 16 + quad * 4;
          int b = m0 >> 8, t0 = m0 & 255;
          uint2 w;
          w.x = pk2(acc[i][j][0], acc[i][j][1]);
          w.y = pk2(acc[i][j][2], acc[i][j][3]);
          *(uint2*)&vb[((b * Hn + hh) * HDn + d) * Tn + t0] = w;
        }
      }
    }
  }
}

// ---------------------------------------------------------------------------
// Flash-chunked attention (R3). Grid = B*H*4; wave w handles ONE q-tile qt in
// {c4, 7-c4, 8+c4, 15-c4} -> identical work per block. Online softmax over
// 32-wide kk chunks; P round-trips through a per-wave LDS buffer (16x40).
// ---------------------------------------------------------------------------
__global__ __launch_bounds__(256) void attn_kernel(
    const u16* __restrict__ q, const u16* __restrict__ k,
    const u16* __restrict__ vT, u16* __restrict__ ao)
{
  __shared__ __align__(16) u16 Ps[4][16 * 40];
  const int tid = threadIdx.x, lane = tid & 63, wave = tid >> 6;
  const int quad = lane >> 4, l16 = lane & 15;
  const int bh = blockIdx.x >> 2, c4 = blockIdx.x & 3;
  const int b = bh / Hn, h = bh % Hn;
  const u16* qg = q + (b * Tn) * Dn + h * HDn;
  const u16* kg = k + (b * Tn) * Dn + h * HDn;
  const u16* vg = vT + bh * (HDn * Tn);
  u16* aog = ao + (b * Tn) * Dn + h * HDn;
  const float c1 = 0.125f * 1.44269504f;  // scale * log2(e)

  const int qt = (wave & 2) ? ((wave & 1) ? 15 - c4 : 8 + c4)
                            : ((wave & 1) ? 7 - c4 : c4);
  const int qglob = qt * 16 + l16;

  const s8v qf0 = *(const s8v*)&qg[qglob * Dn + quad * 8];
  const s8v qf1 = *(const s8v*)&qg[qglob * Dn + 32 + quad * 8];

  float m = -3.0e38f, l = 0.f;
  f4 O[4] = {};
  u16* prow = &Ps[wave][l16 * 40];

  const int nch = qt / 2 + 1;
  for (int c2 = 0; c2 < nch; c2++) {
    const int kk0 = c2 * 32;
    f4 S0 = {0.f, 0.f, 0.f, 0.f}, S1 = S0;
    {
      s8v kf = *(const s8v*)&kg[(kk0 + l16) * Dn + quad * 8];
      S0 = __builtin_amdgcn_mfma_f32_16x16x32_bf16(kf, qf0, S0, 0, 0, 0);
      kf = *(const s8v*)&kg[(kk0 + l16) * Dn + 32 + quad * 8];
      S0 = __builtin_amdgcn_mfma_f32_16x16x32_bf16(kf, qf1, S0, 0, 0, 0);
    }
    if (kk0 + 16 <= qt * 16) {  // second 16-row K tile inside causal bound
      s8v kf = *(const s8v*)&kg[(kk0 + 16 + l16) * Dn + quad * 8];
      S1 = __builtin_amdgcn_mfma_f32_16x16x32_bf16(kf, qf0, S1, 0, 0, 0);
      kf = *(const s8v*)&kg[(kk0 + 16 + l16) * Dn + 32 + quad * 8];
      S1 = __builtin_amdgcn_mfma_f32_16x16x32_bf16(kf, qf1, S1, 0, 0, 0);
    }
    const int kkq = kk0 + quad * 4;
    float cmax = -3.0e38f;
#pragma unroll
    for (int r = 0; r < 4; r++) {
      if (kkq + r <= qglob) cmax = fmaxf(cmax, S0[r]);
      if (kkq + 16 + r <= qglob) cmax = fmaxf(cmax, S1[r]);
    }
    cmax = fmaxf(cmax, __shfl_xor(cmax, 16));
    cmax = fmaxf(cmax, __shfl_xor(cmax, 32));
    const float mnew = fmaxf(m, cmax);
    const float alpha = exp2f((m - mnew) * c1);
    float csum = 0.f;
#pragma unroll
    for (int r = 0; r < 4; r++) {
      float e0 = (kkq + r <= qglob) ? exp2f((S0[r] - mnew) * c1) : 0.f;
      float e1 = (kkq + 16 + r <= qglob) ? exp2f((S1[r] - mnew) * c1) : 0.f;
      S0[r] = e0;
      S1[r] = e1;
      csum += e0 + e1;
    }
    csum += __shfl_xor(csum, 16);
    csum += __shfl_xor(csum, 32);
    l = l * alpha + csum;
    m = mnew;

    uint2 w0, w1;
    w0.x = pk2(S0[0], S0[1]); w0.y = pk2(S0[2], S0[3]);
    w1.x = pk2(S1[0], S1[1]); w1.y = pk2(S1[2], S1[3]);
    *(uint2*)&prow[quad * 4] = w0;
    *(uint2*)&prow[16 + quad * 4] = w1;
#pragma unroll
    for (int dm = 0; dm < 4; dm++) O[dm] = O[dm] * alpha;
    const s8v pf = *(const s8v*)&prow[quad * 8];
#pragma unroll
    for (int dm = 0; dm < 4; dm++) {
      s8v vf = *(const s8v*)&vg[(dm * 16 + l16) * Tn + kk0 + quad * 8];
      O[dm] = __builtin_amdgcn_mfma_f32_16x16x32_bf16(vf, pf, O[dm], 0, 0, 0);
    }
  }

  const float inv = 1.0f / l;
#pragma unroll
  for (int dm = 0; dm < 4; dm++) {
    uint2 w;
    w.x = pk2(O[dm][0] * inv, O[dm][1] * inv);
    w.y = pk2(O[dm][2] * inv, O[dm][3] * inv);
    *(uint2*)&aog[qglob * Dn + dm * 16 + quad * 4] = w;
  }
}

// ---------------------------------------------------------------------------
// LayerNorm: one wave per token (D=384 -> 6 floats/lane), bf16 out.
// ---------------------------------------------------------------------------
__global__ __launch_bounds__(256) void ln_kernel(
    const float* __restrict__ x, const float* __restrict__ sc,
    const float* __restrict__ bi, u16* __restrict__ out)
{
  int tok = blockIdx.x * 4 + (threadIdx.x >> 6);
  int lane = threadIdx.x & 63;
  const float* xr = x + (size_t)tok * Dn;
  float v[6];
  float s = 0.f, sq = 0.f;
#pragma unroll
  for (int i = 0; i < 6; i++) {
    v[i] = xr[lane + 64 * i];
    s += v[i];
    sq += v[i] * v[i];
  }
#pragma unroll
  for (int o = 1; o < 64; o <<= 1) {
    s += __shfl_xor(s, o);
    sq += __shfl_xor(sq, o);
  }
  float mean = s * (1.f / 384.f);
  float var = sq * (1.f / 384.f) - mean * mean;
  float inv = rsqrtf(var + 1e-5f);
  u16* orow = out + (size_t)tok * Dn;
#pragma unroll
  for (int i = 0; i < 6; i++) {
    int c = lane + 64 * i;
    orow[c] = f2b((v[i] - mean) * inv * sc[c] + bi[c]);
  }
}

// x[m][:] = tok_emb[idx[m]][:] + pos_emb[m%T][:]  (float4 per thread)
__global__ __launch_bounds__(256) void embed_kernel(
    const int* __restrict__ idx, const float* __restrict__ tok,
    const float* __restrict__ pos, float* __restrict__ x)
{
  int i = blockIdx.x * 256 + threadIdx.x;  // [0, M*96)
  int m = i / 96, c = (i - m * 96) * 4;
  int t = m & (Tn - 1);
  const float4 tv = *(const float4*)&tok[idx[m] * Dn + c];
  const float4 pv = *(const float4*)&pos[t * Dn + c];
  float4 r;
  r.x = tv.x + pv.x; r.y = tv.y + pv.y; r.z = tv.z + pv.z; r.w = tv.w + pv.w;
  *(float4*)&x[m * Dn + c] = r;
}

// dst[l*lstride + c*R + r] (bf16, zero-filled c>=C) = src[l][r][c] (f32)
__global__ __launch_bounds__(256) void tcvt_kernel(
    const float* __restrict__ src, u16* __restrict__ dst,
    int R, int C, int Cpad, int lstride, int total)
{
  int t = blockIdx.x * 256 + threadIdx.x;
  if (t >= total) return;
  int r = t % R;
  int c = (t / R) % Cpad;
  int l = t / (R * Cpad);
  float v = (c < C) ? src[l * R * C + r * C + c] : 0.f;
  dst[l * lstride + c * R + r] = f2b(v);
}

extern "C" void kernel_launch(void* const* d_in, const int* in_sizes, int n_in,
                              void* d_out, int out_size, void* d_ws, size_t ws_size,
                              hipStream_t stream)
{
  (void)in_sizes; (void)n_in; (void)out_size;
  const int*   idx     = (const int*)d_in[0];
  const float* tok_emb = (const float*)d_in[1];
  const float* pos_emb = (const float*)d_in[2];
  const float* ln1_s   = (const float*)d_in[3];
  const float* ln1_b   = (const float*)d_in[4];
  const float* wq      = (const float*)d_in[5];
  const float* wk      = (const float*)d_in[6];
  const float* wv      = (const float*)d_in[7];
  const float* wo      = (const float*)d_in[8];
  const float* bo      = (const float*)d_in[9];
  const float* ln2_s   = (const float*)d_in[10];
  const float* ln2_b   = (const float*)d_in[11];
  const float* w1      = (const float*)d_in[12];
  const float* b1      = (const float*)d_in[13];
  const float* w2      = (const float*)d_in[14];
  const float* b2      = (const float*)d_in[15];
  const float* lnf_s   = (const float*)d_in[16];
  const float* lnf_b   = (const float*)d_in[17];
  const float* head_w  = (const float*)d_in[18];
  const float* head_b  = (const float*)d_in[19];
  float* out = (float*)d_out;

  // workspace layout (bytes)
  char* ws = (char*)d_ws;
  float* x  = (float*)(ws + 0);             // 50,331,648  fp32 residual stream
  u16*   h  = (u16*)(ws + 50331648);        // 25,165,824  LN output (bf16)
  u16*   qb = (u16*)(ws + 75497472);        // 25,165,824  (q,k,v contiguous!)
  u16*   kb = (u16*)(ws + 100663296);       // 25,165,824
  u16*   vb = (u16*)(ws + 125829120);       // 25,165,824  V^T [(b,h)][d][t]
  u16*   ab = (u16*)(ws + 150994944);       // 25,165,824  attn out
  u16*   f1 = qb;                           // alias (q..ab region) for FFN1 out
  u16* qkvT = (u16*)(ws + 176160768);       // 6 * 1152*384 els (q rows, k rows, v rows)
  u16* woT  = qkvT + 6 * 442368;            // 6 * 147456
  u16* w1T  = woT + 6 * 147456;             // 6 * 589824  [FF,K=D]
  u16* w2T  = w1T + 6 * 589824;             // 6 * 589824  [D,K=FF]
  u16* hdT  = w2T + 6 * 589824;             // 128*384, N padded 95->128
  if (ws_size < (size_t)197492736) return;

  int tot = 6 * 384 * 384;
  tcvt_kernel<<<(tot + 255) / 256, 256, 0, stream>>>(wq, qkvT, 384, 384, 384, 442368, tot);
  tcvt_kernel<<<(tot + 255) / 256, 256, 0, stream>>>(wk, qkvT + 384 * 384, 384, 384, 384, 442368, tot);
  tcvt_kernel<<<(tot + 255) / 256, 256, 0, stream>>>(wv, qkvT + 768 * 384, 384, 384, 384, 442368, tot);
  tcvt_kernel<<<(tot + 255) / 256, 256, 0, stream>>>(wo, woT, 384, 384, 384, 147456, tot);
  tot = 6 * 1536 * 384;
  tcvt_kernel<<<(tot + 255) / 256, 256, 0, stream>>>(w1, w1T, 384, 1536, 1536, 589824, tot);
  tcvt_kernel<<<(tot + 255) / 256, 256, 0, stream>>>(w2, w2T, 1536, 384, 384, 589824, tot);
  tot = 128 * 384;
  tcvt_kernel<<<(tot + 255) / 256, 256, 0, stream>>>(head_w, hdT, 384, 95, 128, 49152, tot);

  embed_kernel<<<(Mn * 96) / 256, 256, 0, stream>>>(idx, tok_emb, pos_emb, x);

  for (int l = 0; l < 6; l++) {
    ln_kernel<<<Mn / 4, 256, 0, stream>>>(x, ln1_s + l * Dn, ln1_b + l * Dn, h);
    gemm_bt<4, false><<<2304, 256, 0, stream>>>(h, qkvT + l * 442368, nullptr, nullptr, qb, 1152, Dn, 9);
    attn_kernel<<<Bn * Hn * 4, 256, 0, stream>>>(qb, kb, vb, ab);
    gemm_bt<1, false><<<768, 256, 0, stream>>>(ab, woT + l * 147456, bo + l * Dn, x, x, Dn, Dn, 3);
    ln_kernel<<<Mn / 4, 256, 0, stream>>>(x, ln2_s + l * Dn, ln2_b + l * Dn, h);
    gemm_bt<0, true><<<3072, 256, 0, stream>>>(h, w1T + l * 589824, b1 + l * FFn, nullptr, f1, FFn, Dn, 12);
    gemm_bt<1, false><<<768, 256, 0, stream>>>(f1, w2T + l * 589824, b2 + l * Dn, x, x, Dn, FFn, 3);
  }
  ln_kernel<<<Mn / 4, 256, 0, stream>>>(x, lnf_s, lnf_b, h);
  gemm_bt<3, false><<<256, 256, 0, stream>>>(h, hdT, head_b, nullptr, out, 128, Dn, 1);
}